// Round 8
// baseline (432.439 us; speedup 1.0000x reference)
//
#include <hip/hip_runtime.h>
#include <hip/hip_bf16.h>

// VoxelGrid: 10M events -> (10, 720, 1280) fp32 grid, bilinear splat in time.
// R1: naive 20M device atomics -> 21 G atomics/s (958 us).
// R2-R4: 720-bucket sort: partial-line L2 evictions -> 4-5x write amp ~190 us.
// R5: 240 coarse buckets (y/3): write amp fixed, total 415.
// R6/R7: p3 invariant at ~122 us under residency/decode/bank changes.
// Unified model: scattered LDS atomics retire ~1 lane/cycle/CU; p2 (20M
//   lanes: hist+cursor) and p3 (20M lanes: 2 ds_add/record) both floor at
//   ~80-120 us at observed effective clock.
// R8: p2 drops pass-A histogram -> fixed-size per-(block,bucket) runs
//   (ub slots, adaptive from ws, >=176), single streaming pass, 10M LDS
//   lanes (cursor only). Run overflow -> oflist, drained exactly by p4.
//   Pad slots are zero words; p3 skips w==0 (tn=0 -> exact).

#define NUM_BINS 5
#define DT_OFFSET 1
#define GW 1280
#define GH 720
#define NSLAB (NUM_BINS * 2)   // 10 (bin, polarity) slabs
#define NGRP 240               // coarse buckets (y/3)
#define NB2 256                // phase-2 blocks (fixed: capg = NB2 * ub)
#define GWP (GW + 4)           // padded x-stride in p3 tile
#define CURSOR_BYTES 4096      // [0] = overflow counter
#define OF_RESERVE (512*1024)  // minimum overflow list bytes
#define UB_MIN 176             // min slots per (block,bucket) run
#define UB_MAX 208             // cap (bounds p3 pad-read waste)

// Packed record: [q:16 | ylo:2 | pos:1 | xi:11], tn ~= q/65535, y = 3*g + ylo.
// Zero word = pad (or tn==0 event, which contributes exactly +0.0) -> skipped.

// ---------------- Phase 2: single-pass bucket scatter -----------------------
__global__ __launch_bounds__(1024) void p2_bucket(
        const float4* __restrict__ ev, int n,
        unsigned* __restrict__ ofcnt, unsigned* __restrict__ bucket,
        unsigned* __restrict__ oflist, int ofcap, int ub,
        const int* __restrict__ ct_p, const int* __restrict__ dt_p) {
    __shared__ unsigned hist[NGRP];   // within-run cursor

    const int chunk = (n + gridDim.x - 1) / gridDim.x;
    const int start = blockIdx.x * chunk;
    const int end   = min(n, start + chunk);
    const int capg  = NB2 * ub;

    if (threadIdx.x < NGRP) hist[threadIdx.x] = 0u;
    __syncthreads();

    const int ct  = *ct_p;
    const int dti = *dt_p;
    const float bt  = (float)(ct - dti);
    const float dtf = (float)(dti + DT_OFFSET);

    // stream: coalesced read -> decode -> LDS cursor atomic -> scattered store
    for (int i = start + (int)threadIdx.x; i < end; i += blockDim.x) {
        float4 e = ev[i];
        int yi  = (int)e.z;
        int xi  = (int)e.y;
        int pos = (e.w > 0.0f) ? 1 : 0;
        int g   = yi / 3;
        int ylo = yi - 3 * g;
        float tn = (e.x - bt) / dtf;               // in [0, 1)
        unsigned q = (unsigned)(tn * 65535.0f + 0.5f);
        if (q > 65535u) q = 65535u;
        unsigned word = (q << 14) | ((unsigned)ylo << 12)
                      | ((unsigned)pos << 11) | (unsigned)xi;
        unsigned j = atomicAdd(&hist[g], 1u);      // the ONLY LDS atomic
        if (j < (unsigned)ub) {
            bucket[(size_t)g * capg + (size_t)blockIdx.x * ub + j] = word;
        } else {
            unsigned o = atomicAdd(ofcnt, 1u);     // rare run overflow
            if (o < (unsigned)ofcap) {
                oflist[2 * o]     = (unsigned)yi;
                oflist[2 * o + 1] = word;
            }
        }
    }
    __syncthreads();

    // zero-fill the pad tail of each of this block's runs (skipped by p3)
    for (int g = threadIdx.x; g < NGRP; g += blockDim.x) {
        unsigned c = hist[g];
        if (c > (unsigned)ub) c = (unsigned)ub;
        unsigned* run = bucket + (size_t)g * capg + (size_t)blockIdx.x * ub;
        for (unsigned j = c; j < (unsigned)ub; ++j) run[j] = 0u;
    }
}

// ---------------- Phase 3: one block per bucket, LDS accumulate -------------
// Tile: [slab 0..9][ylo 0..2][x) stride GWP; atomic pair 6*GWP apart.
__global__ __launch_bounds__(1024) void p3_accum(
        const unsigned* __restrict__ bucket, float* __restrict__ out, int ub) {
    __shared__ float tile[NSLAB * 3 * GWP];   // 154,080 B
    const int g    = blockIdx.x;
    const int capg = NB2 * ub;

    for (int k = threadIdx.x; k < NSLAB * 3 * GWP; k += blockDim.x)
        tile[k] = 0.0f;
    __syncthreads();

    const uint4* bk4 = (const uint4*)(bucket + (size_t)g * capg);
    const unsigned n4 = (unsigned)(capg / 4);   // ub multiple of 16 -> exact

    for (unsigned j = threadIdx.x; j < n4; j += blockDim.x) {
        uint4 w4 = bk4[j];
        #pragma unroll
        for (int c = 0; c < 4; ++c) {
            unsigned w = (c == 0) ? w4.x : (c == 1) ? w4.y : (c == 2) ? w4.z : w4.w;
            if (w == 0u) continue;                 // pad (or exact-zero event)
            int   xi  = (int)(w & 0x7FFu);
            int   pos = (int)((w >> 11) & 1u);
            int   ylo = (int)((w >> 12) & 3u);
            float tn  = (float)(w >> 14) * (1.0f / 65535.0f);
            float bf  = (NUM_BINS - 1.0f) * tn;
            float back = floorf(bf);
            float fw   = bf - back;
            int   b    = (int)back;
            if (b > NUM_BINS - 2) b = NUM_BINS - 2;   // can't fire (q<=65534)
            int   idx  = ((b * 2 + pos) * 3 + ylo) * GWP + xi;
            atomicAdd(&tile[idx],           (1.0f - fw) * tn);  // ds_add_f32
            atomicAdd(&tile[idx + 6 * GWP], fw * tn);
        }
    }
    __syncthreads();

    // exclusive coalesced float4 writeout: 3 rows x 10 slabs
    for (int k = threadIdx.x; k < NSLAB * 3 * (GW / 4); k += blockDim.x) {
        int r   = k / (GW / 4);       // 0..29 = s*3 + ylo
        int x4  = k % (GW / 4);
        int s   = r / 3;
        int ylo = r - 3 * s;
        int y   = 3 * g + ylo;
        ((float4*)(out + ((size_t)s * GH + y) * GW))[x4] =
            ((const float4*)(tile + r * GWP))[x4];
    }
}

// ---------------- Phase 4: drain overflow list ------------------------------
__global__ void p4_overflow(const unsigned* __restrict__ ofcnt,
                            const unsigned* __restrict__ oflist, int ofcap,
                            float* __restrict__ out) {
    unsigned nof = *ofcnt;
    if (nof > (unsigned)ofcap) nof = (unsigned)ofcap;
    for (unsigned k = blockIdx.x * blockDim.x + threadIdx.x; k < nof;
         k += gridDim.x * blockDim.x) {
        unsigned yi = oflist[2 * k];
        unsigned w  = oflist[2 * k + 1];
        int   xi  = (int)(w & 0x7FFu);
        int   pos = (int)((w >> 11) & 1u);
        float tn  = (float)(w >> 14) * (1.0f / 65535.0f);
        float bf  = (NUM_BINS - 1.0f) * tn;
        float back = floorf(bf);
        float fw   = bf - back;
        int   b    = (int)back;
        if (b > NUM_BINS - 2) b = NUM_BINS - 2;
        atomicAdd(&out[((size_t)(b * 2 + pos) * GH + yi) * GW + xi],
                  (1.0f - fw) * tn);
        atomicAdd(&out[((size_t)((b + 1) * 2 + pos) * GH + yi) * GW + xi],
                  fw * tn);
    }
}

// ---------------- Fallback: R1 naive atomic kernel (if ws too small) --------
__global__ void voxel_scatter_kernel(const float4* __restrict__ events,
                                     float* __restrict__ out, int n,
                                     const int* __restrict__ ct_p,
                                     const int* __restrict__ dt_p,
                                     const int* __restrict__ w_p,
                                     const int* __restrict__ h_p) {
    int i = blockIdx.x * blockDim.x + threadIdx.x;
    if (i >= n) return;
    const int ct = *ct_p, dti = *dt_p, W = *w_p, H = *h_p;
    const float bt  = (float)(ct - dti);
    const float dtf = (float)(dti + DT_OFFSET);
    float4 e = events[i];
    const float tn    = (e.x - bt) / dtf;
    const float bin_f = (NUM_BINS - 1.0f) * tn;
    const float back  = floorf(bin_f);
    const float fwd_w = bin_f - back;
    const int back_i = (int)back;
    const int pos    = (e.w > 0.0f) ? 1 : 0;
    const int xi = (int)e.y, yi = (int)e.z;
    const int plane = H * W, slab = 2 * plane;
    const int base = (back_i * 2 + pos) * plane + yi * W + xi;
    atomicAdd(&out[base],        (1.0f - fwd_w) * tn);
    atomicAdd(&out[base + slab], fwd_w * tn);
}

extern "C" void kernel_launch(void* const* d_in, const int* in_sizes, int n_in,
                              void* d_out, int out_size, void* d_ws, size_t ws_size,
                              hipStream_t stream) {
    const float4* events = (const float4*)d_in[0];
    const int* curr_time = (const int*)d_in[1];
    const int* delta_t   = (const int*)d_in[2];
    const int* width     = (const int*)d_in[3];
    const int* height    = (const int*)d_in[4];
    float* out = (float*)d_out;
    const int n = in_sizes[0] / 4;

    // ws layout: [ofcnt 4KB][bucket NGRP * NB2*ub * 4B][overflow list (rest)]
    // adaptive ub: largest 16-multiple that leaves OF_RESERVE, clamped.
    int ub = 0;
    if (ws_size > CURSOR_BYTES + OF_RESERVE) {
        size_t avail = ws_size - CURSOR_BYTES - OF_RESERVE;
        ub = (int)((avail / ((size_t)NGRP * NB2 * sizeof(unsigned)))
                   & ~(size_t)15);
        if (ub > UB_MAX) ub = UB_MAX;
    }

    if (ub >= UB_MIN) {
        const int capg = NB2 * ub;
        unsigned* ofcnt  = (unsigned*)d_ws;
        unsigned* bucket = (unsigned*)((char*)d_ws + CURSOR_BYTES);
        unsigned* oflist = bucket + (size_t)NGRP * capg;
        int ofcap = (int)((ws_size - CURSOR_BYTES
                           - (size_t)NGRP * capg * sizeof(unsigned))
                          / (2 * sizeof(unsigned)));
        hipMemsetAsync(ofcnt, 0, 64, stream);
        p2_bucket<<<NB2, 1024, 0, stream>>>(events, n, ofcnt, bucket,
                                            oflist, ofcap, ub,
                                            curr_time, delta_t);
        p3_accum<<<NGRP, 1024, 0, stream>>>(bucket, out, ub);
        p4_overflow<<<64, 256, 0, stream>>>(ofcnt, oflist, ofcap, out);
    } else {
        hipMemsetAsync(out, 0, (size_t)out_size * sizeof(float), stream);
        const int block = 256;
        const int grid  = (n + block - 1) / block;
        voxel_scatter_kernel<<<grid, block, 0, stream>>>(events, out, n,
                                                         curr_time, delta_t,
                                                         width, height);
    }
}

// Round 9
// 396.912 us; speedup vs baseline: 1.0895x; 1.0895x over previous
//
#include <hip/hip_runtime.h>
#include <hip/hip_bf16.h>

// VoxelGrid: 10M events -> (10, 720, 1280) fp32 grid, bilinear splat in time.
// R1: naive 20M device atomics -> 21 G atomics/s (958 us).
// R2-R4: 720-bucket sort: partial-line L2 evictions -> 4-5x write amp ~190 us.
// R5: 240 coarse buckets (y/3): write amp fixed, total 415.
// R6/R7: p3 invariant ~122 us under residency/decode/bank changes.
// R8: removing p2's register-batched scatter REGRESSED p2 (122->143) despite
//   halving LDS atomics + FETCH -> both kernels are latency-chain bound
//   (~4 waves/SIMD can't hide load/atomic latency when ops are dependent).
// R9: p2 = exact R7 (register arrays, proven 122). p3 = R7 + software
//   pipelining: 4 independent uint4 loads in flight per iteration (MLP 4x).

#define NUM_BINS 5
#define DT_OFFSET 1
#define GW 1280
#define GH 720
#define NSLAB (NUM_BINS * 2)   // 10 (bin, polarity) slabs
#define NGRP 240               // coarse buckets (y/3)
#define NB2 256                // phase-2 blocks
#define ITERS 40               // events per thread in p2 (256*1024*40 >= 10M)
#define GWP (GW + 4)           // padded x-stride in p3 tile (bank spacing)
#define CURSOR_BYTES 4096      // cursor[0..239] buckets, cursor[240] overflow
#define OF_RESERVE (512*1024)  // overflow list reserve at ws tail
#define MIN_CAPG 45056         // slots/bucket (mean ~43.7K incl pad, +6 sigma)

// Packed record: [q:16 | ylo:2 | pos:1 | xi:11], tn ~= q/65535, y = 3*g + ylo.
// Zero word decodes to tn=0 -> contributes +0.0 (pad slots are harmless).

// ---------------- Phase 2: bucket events by y/3 (single global read) --------
__global__ __launch_bounds__(1024) void p2_bucket(
        const float4* __restrict__ ev, int n,
        unsigned* __restrict__ cursor, unsigned* __restrict__ bucket,
        unsigned* __restrict__ oflist, int ofcap, int capg,
        const int* __restrict__ ct_p, const int* __restrict__ dt_p) {
    __shared__ unsigned hist[NGRP];
    __shared__ unsigned base[NGRP];

    const int chunk = (n + gridDim.x - 1) / gridDim.x;
    const int start = blockIdx.x * chunk;
    const int end   = min(n, start + chunk);

    if (threadIdx.x < NGRP) hist[threadIdx.x] = 0u;
    __syncthreads();

    const int ct  = *ct_p;
    const int dti = *dt_p;
    const float bt  = (float)(ct - dti);
    const float dtf = (float)(dti + DT_OFFSET);

    // pass A: coalesced float4 read, decode into REGISTER arrays, count hist
    unsigned wk[ITERS];   // packed record
    int      gk[ITERS];   // bucket id, -1 = invalid
    #pragma unroll
    for (int k = 0; k < ITERS; ++k) {
        int i = start + (int)threadIdx.x + k * 1024;
        gk[k] = -1;
        wk[k] = 0u;
        if (i < end) {
            float4 e = ev[i];
            int yi  = (int)e.z;
            int xi  = (int)e.y;
            int pos = (e.w > 0.0f) ? 1 : 0;
            int g   = yi / 3;
            int ylo = yi - 3 * g;
            float tn = (e.x - bt) / dtf;           // in [0, 1)
            unsigned q = (unsigned)(tn * 65535.0f + 0.5f);
            if (q > 65535u) q = 65535u;
            wk[k] = (q << 14) | ((unsigned)ylo << 12)
                  | ((unsigned)pos << 11) | (unsigned)xi;
            gk[k] = g;
            atomicAdd(&hist[g], 1u);
        }
    }
    __syncthreads();

    // reserve 64B-aligned runs in the global bucket; zero pad slots
    if (threadIdx.x < NGRP) {
        unsigned k = threadIdx.x;
        unsigned c = hist[k];
        if (c) {
            unsigned r = (c + 15u) & ~15u;
            unsigned b = atomicAdd(&cursor[k], r);
            base[k] = b;
            unsigned* bk = bucket + (size_t)k * capg;
            for (unsigned j = c; j < r; ++j) {
                unsigned slot = b + j;
                if (slot < (unsigned)capg) bk[slot] = 0u;
            }
        } else {
            base[k] = 0u;
        }
        hist[k] = 0u;          // becomes pass-B cursor
    }
    __syncthreads();

    // pass B: scatter straight from registers (no re-read, no re-decode)
    #pragma unroll
    for (int k = 0; k < ITERS; ++k) {
        if (gk[k] >= 0) {
            int g = gk[k];
            unsigned j    = atomicAdd(&hist[g], 1u);
            unsigned slot = base[g] + j;
            if (slot < (unsigned)capg) {
                bucket[(size_t)g * capg + slot] = wk[k];
            } else {
                unsigned o = atomicAdd(&cursor[NGRP], 1u);
                if (o < (unsigned)ofcap) {
                    oflist[2 * o]     = (unsigned)(3 * g + ((wk[k] >> 12) & 3u));
                    oflist[2 * o + 1] = wk[k];
                }
            }
        }
    }
}

// ---------------- Phase 3: one block per bucket, pipelined loads ------------
// Tile: [slab 0..9][ylo 0..2][x) stride GWP; atomic pair 6*GWP apart.
__device__ __forceinline__ void p3_process(unsigned w, float* tile) {
    if (w == 0u) return;                       // pad (or exact-zero event)
    int   xi  = (int)(w & 0x7FFu);
    int   pos = (int)((w >> 11) & 1u);
    int   ylo = (int)((w >> 12) & 3u);
    float qf  = (float)(w >> 14);
    float tn  = qf * (1.0f / 65535.0f);
    float bf  = qf * (4.0f / 65535.0f);
    float back = floorf(bf);
    float fw   = bf - back;
    int   b    = (int)back;
    if (b > NUM_BINS - 2) b = NUM_BINS - 2;    // can't fire (q <= 65535)
    int   idx  = ((b * 2 + pos) * 3 + ylo) * GWP + xi;
    atomicAdd(&tile[idx],           (1.0f - fw) * tn);   // ds_add_f32
    atomicAdd(&tile[idx + 6 * GWP], fw * tn);
}

__global__ __launch_bounds__(1024) void p3_accum(
        const unsigned* __restrict__ cursor, const unsigned* __restrict__ bucket,
        float* __restrict__ out, int capg) {
    __shared__ float tile[NSLAB * 3 * GWP];   // 154,080 B (<= 160 KiB)
    const int g = blockIdx.x;

    for (int k = threadIdx.x; k < NSLAB * 3 * GWP; k += blockDim.x)
        tile[k] = 0.0f;
    __syncthreads();

    unsigned cnt = cursor[g];
    if (cnt > (unsigned)capg) cnt = (unsigned)capg;   // rest went to overflow
    const uint4* bk4 = (const uint4*)(bucket + (size_t)g * capg);
    unsigned n4 = cnt / 4;                            // cnt is multiple of 16

    // batch 4 independent uint4 loads per outer iteration (MLP 4x):
    const uint4 z4 = make_uint4(0u, 0u, 0u, 0u);
    for (unsigned j0 = threadIdx.x; j0 < n4; j0 += 4u * 1024u) {
        unsigned j1 = j0 + 1024u, j2 = j0 + 2048u, j3 = j0 + 3072u;
        uint4 a = bk4[j0];
        uint4 b = (j1 < n4) ? bk4[j1] : z4;
        uint4 c = (j2 < n4) ? bk4[j2] : z4;
        uint4 d = (j3 < n4) ? bk4[j3] : z4;
        p3_process(a.x, tile); p3_process(a.y, tile);
        p3_process(a.z, tile); p3_process(a.w, tile);
        p3_process(b.x, tile); p3_process(b.y, tile);
        p3_process(b.z, tile); p3_process(b.w, tile);
        p3_process(c.x, tile); p3_process(c.y, tile);
        p3_process(c.z, tile); p3_process(c.w, tile);
        p3_process(d.x, tile); p3_process(d.y, tile);
        p3_process(d.z, tile); p3_process(d.w, tile);
    }
    __syncthreads();

    // exclusive coalesced float4 writeout: 3 rows x 10 slabs
    for (int k = threadIdx.x; k < NSLAB * 3 * (GW / 4); k += blockDim.x) {
        int r   = k / (GW / 4);       // 0..29 = s*3 + ylo
        int x4  = k % (GW / 4);
        int s   = r / 3;
        int ylo = r - 3 * s;
        int y   = 3 * g + ylo;
        ((float4*)(out + ((size_t)s * GH + y) * GW))[x4] =
            ((const float4*)(tile + r * GWP))[x4];
    }
}

// ---------------- Phase 4: drain overflow list (usually empty) --------------
__global__ void p4_overflow(const unsigned* __restrict__ cursor,
                            const unsigned* __restrict__ oflist, int ofcap,
                            float* __restrict__ out) {
    unsigned nof = cursor[NGRP];
    if (nof > (unsigned)ofcap) nof = (unsigned)ofcap;
    for (unsigned k = blockIdx.x * blockDim.x + threadIdx.x; k < nof;
         k += gridDim.x * blockDim.x) {
        unsigned yi = oflist[2 * k];
        unsigned w  = oflist[2 * k + 1];
        int   xi  = (int)(w & 0x7FFu);
        int   pos = (int)((w >> 11) & 1u);
        float tn  = (float)(w >> 14) * (1.0f / 65535.0f);
        float bf  = (NUM_BINS - 1.0f) * tn;
        float back = floorf(bf);
        float fw   = bf - back;
        int   b    = (int)back;
        if (b > NUM_BINS - 2) b = NUM_BINS - 2;
        atomicAdd(&out[((size_t)(b * 2 + pos) * GH + yi) * GW + xi],
                  (1.0f - fw) * tn);
        atomicAdd(&out[((size_t)((b + 1) * 2 + pos) * GH + yi) * GW + xi],
                  fw * tn);
    }
}

// ---------------- Fallback: R1 naive atomic kernel (if ws too small) --------
__global__ void voxel_scatter_kernel(const float4* __restrict__ events,
                                     float* __restrict__ out, int n,
                                     const int* __restrict__ ct_p,
                                     const int* __restrict__ dt_p,
                                     const int* __restrict__ w_p,
                                     const int* __restrict__ h_p) {
    int i = blockIdx.x * blockDim.x + threadIdx.x;
    if (i >= n) return;
    const int ct = *ct_p, dti = *dt_p, W = *w_p, H = *h_p;
    const float bt  = (float)(ct - dti);
    const float dtf = (float)(dti + DT_OFFSET);
    float4 e = events[i];
    const float tn    = (e.x - bt) / dtf;
    const float bin_f = (NUM_BINS - 1.0f) * tn;
    const float back  = floorf(bin_f);
    const float fwd_w = bin_f - back;
    const int back_i = (int)back;
    const int pos    = (e.w > 0.0f) ? 1 : 0;
    const int xi = (int)e.y, yi = (int)e.z;
    const int plane = H * W, slab = 2 * plane;
    const int base = (back_i * 2 + pos) * plane + yi * W + xi;
    atomicAdd(&out[base],        (1.0f - fwd_w) * tn);
    atomicAdd(&out[base + slab], fwd_w * tn);
}

extern "C" void kernel_launch(void* const* d_in, const int* in_sizes, int n_in,
                              void* d_out, int out_size, void* d_ws, size_t ws_size,
                              hipStream_t stream) {
    const float4* events = (const float4*)d_in[0];
    const int* curr_time = (const int*)d_in[1];
    const int* delta_t   = (const int*)d_in[2];
    const int* width     = (const int*)d_in[3];
    const int* height    = (const int*)d_in[4];
    float* out = (float*)d_out;
    const int n = in_sizes[0] / 4;

    // ws layout: [cursor 4KB][bucket NGRP*capg*4B][overflow list (rest)]
    int capg = 0;
    if (ws_size > CURSOR_BYTES + OF_RESERVE)
        capg = (int)(((ws_size - CURSOR_BYTES - OF_RESERVE)
                      / (NGRP * sizeof(unsigned))) & ~(size_t)15);

    if (capg >= MIN_CAPG && n <= NB2 * 1024 * ITERS) {
        unsigned* cursor = (unsigned*)d_ws;
        unsigned* bucket = (unsigned*)((char*)d_ws + CURSOR_BYTES);
        unsigned* oflist = bucket + (size_t)NGRP * capg;
        int ofcap = (int)((ws_size - CURSOR_BYTES
                           - (size_t)NGRP * capg * sizeof(unsigned))
                          / (2 * sizeof(unsigned)));
        hipMemsetAsync(cursor, 0, CURSOR_BYTES, stream);
        p2_bucket<<<NB2, 1024, 0, stream>>>(events, n, cursor, bucket,
                                            oflist, ofcap, capg,
                                            curr_time, delta_t);
        p3_accum<<<NGRP, 1024, 0, stream>>>(cursor, bucket, out, capg);
        p4_overflow<<<64, 256, 0, stream>>>(cursor, oflist, ofcap, out);
    } else {
        hipMemsetAsync(out, 0, (size_t)out_size * sizeof(float), stream);
        const int block = 256;
        const int grid  = (n + block - 1) / block;
        voxel_scatter_kernel<<<grid, block, 0, stream>>>(events, out, n,
                                                         curr_time, delta_t,
                                                         width, height);
    }
}